// Round 2
// baseline (1080.733 us; speedup 1.0000x reference)
//
#include <hip/hip_runtime.h>

#define NF   39
#define EMB  64
#define NPAIR 741   // C(39,2)

// out[b, pair(p,q), n] = sum_m x[(n-m)&63] * y[m]   (circular convolution)
//
// One wave per block; p and q derive ONLY from blockIdx -> all control flow
// and all y-addresses are uniform -> compiler emits scalar (s_load) reads of
// y, consumed as the SGPR operand of v_fmac_f32. No LDS at all (the R1
// version was DS-pipe-throughput-bound: 48.6M ds_read_b128 x 12cyc/CU = 950us).
//
// Load balance: block j handles p = j and p = 37-j -> (38-j) + (j+1) = 39
// pairs per block, constant.
__global__ __launch_bounds__(64) void holo_conv_kernel(
    const float* __restrict__ emb,   // [B, 39, 64]
    float* __restrict__ out)         // [B, 741, 64]
{
    const int b    = blockIdx.x;
    const int j    = blockIdx.y;     // 0..18
    const int lane = threadIdx.x;    // 0..63

    const float* __restrict__ ebase = emb + (size_t)b * (NF * EMB);
    float* __restrict__ obase = out + (size_t)b * NPAIR * EMB;

    #pragma unroll
    for (int pi = 0; pi < 2; ++pi) {
        const int p = (pi == 0) ? j : (37 - j);   // uniform (blockIdx-derived)

        // Rotated x in registers: xr[m] = x[(lane - m) & 63].
        // 64 divergent loads within one 256B row -> L1-resident gather.
        const float* __restrict__ xrow = ebase + p * EMB;
        float xr[EMB];
        #pragma unroll
        for (int m = 0; m < EMB; ++m) xr[m] = xrow[(lane - m) & 63];

        const int fbase = 38 * p - (p * (p - 1)) / 2;  // flat index of pair (p, p+1)

        for (int q = p + 1; q < NF; ++q) {             // uniform loop
            const float4* __restrict__ y4 = (const float4*)(ebase + q * EMB);
            float a0 = 0.f, a1 = 0.f, a2 = 0.f, a3 = 0.f;
            #pragma unroll
            for (int mm = 0; mm < EMB / 4; ++mm) {
                const float4 yv = y4[mm];  // uniform address, readonly -> s_load
                a0 = fmaf(xr[4 * mm + 0], yv.x, a0);
                a1 = fmaf(xr[4 * mm + 1], yv.y, a1);
                a2 = fmaf(xr[4 * mm + 2], yv.z, a2);
                a3 = fmaf(xr[4 * mm + 3], yv.w, a3);
            }
            const size_t oidx = (size_t)(fbase + (q - p - 1)) * EMB + lane;
            obase[oidx] = (a0 + a1) + (a2 + a3);       // coalesced 256B store
        }
    }
}

extern "C" void kernel_launch(void* const* d_in, const int* in_sizes, int n_in,
                              void* d_out, int out_size, void* d_ws, size_t ws_size,
                              hipStream_t stream) {
    const float* emb = (const float*)d_in[0];
    float* out = (float*)d_out;

    const int batch = in_sizes[0] / (NF * EMB);
    dim3 grid(batch, 19);           // 19 blocks cover p = 0..37 (j and 37-j)
    holo_conv_kernel<<<grid, 64, 0, stream>>>(emb, out);
}

// Round 3
// 453.922 us; speedup vs baseline: 2.3809x; 2.3809x over previous
//
#include <hip/hip_runtime.h>

#define NF   39
#define EMB  64
#define NPAIR 741   // C(39,2)

typedef float f32x16 __attribute__((ext_vector_type(16)));

// out[b, pair(p,q), n] = sum_m x[(n-m)&63] * y[m]   (circular convolution)
//
// R1 was DS-pipe-bound: 16 ds_read_b128 per pair x 12cyc = 950us/CU.
// R3: y (wave-uniform) comes from the SCALAR pipe: s_load_dwordx16 x4 from
// global (L2-hot after LDS staging), consumed as the SGPR src of v_fmac_f32.
// xr (per-lane rotated x) gathered from LDS once per p-group (amortized).
// One block per batch keeps FETCH at ~38MB (R2's b-fastest grid thrashed L2
// to 574MB and ran 1-wave blocks at 23% occupancy / 36% VALUBusy).
__global__ __launch_bounds__(256) void holo_conv_kernel(
    const float* __restrict__ emb,   // [B, 39, 64]
    float* __restrict__ out)         // [B, 741, 64]
{
    __shared__ __align__(16) float smem[NF * EMB];  // 9984 B

    const int b    = blockIdx.x;
    const int tid  = threadIdx.x;
    const int lane = tid & 63;
    // readfirstlane -> compiler-proven wave-uniform; all downstream p/q/fbase
    // arithmetic stays scalar so the "s" asm constraints are satisfiable.
    const int w    = __builtin_amdgcn_readfirstlane(tid >> 6);

    const float* __restrict__ ebase = emb + (size_t)b * (NF * EMB);
    for (int i = tid; i < NF * EMB; i += 256) smem[i] = ebase[i];
    __syncthreads();

    float* __restrict__ obase = out + (size_t)b * NPAIR * EMB;

    // Static p-partition balancing pairs/wave: 180/183/188/190.
    const int PS0 = (w == 0) ? 0 : (w == 1) ? 5 : (w == 2) ? 11 : 19;
    const int PS1 = (w == 0) ? 5 : (w == 1) ? 11 : (w == 2) ? 19 : 38;

    for (int p = PS0; p < PS1; ++p) {
        // xr[m] = x[(lane - m) & 63] in VGPRs. For fixed m the 64 lanes read
        // a rotation of 64 consecutive floats -> 2 lanes/bank -> free.
        float xr[EMB];
        const int xbase = p * EMB;
        #pragma unroll
        for (int m = 0; m < EMB; ++m) xr[m] = smem[xbase + ((lane - m) & 63)];

        const int fbase = 38 * p - (p * (p - 1)) / 2;  // flat index of (p, p+1)

        for (int q = p + 1; q < NF; ++q) {
            const float* yrow = ebase + q * EMB;   // uniform scalar address
            f32x16 y0, y1, y2, y3;                 // 64 SGPRs
            asm volatile(
                "s_load_dwordx16 %0, %4, 0x0\n\t"
                "s_load_dwordx16 %1, %4, 0x40\n\t"
                "s_load_dwordx16 %2, %4, 0x80\n\t"
                "s_load_dwordx16 %3, %4, 0xc0\n\t"
                "s_waitcnt lgkmcnt(0)"
                : "=s"(y0), "=s"(y1), "=s"(y2), "=s"(y3)
                : "s"(yrow));

            float a0 = 0.f, a1 = 0.f, a2 = 0.f, a3 = 0.f;
            #pragma unroll
            for (int mm = 0; mm < 16; ++mm) a0 = fmaf(xr[mm],      y0[mm], a0);
            #pragma unroll
            for (int mm = 0; mm < 16; ++mm) a1 = fmaf(xr[16 + mm], y1[mm], a1);
            #pragma unroll
            for (int mm = 0; mm < 16; ++mm) a2 = fmaf(xr[32 + mm], y2[mm], a2);
            #pragma unroll
            for (int mm = 0; mm < 16; ++mm) a3 = fmaf(xr[48 + mm], y3[mm], a3);

            const size_t oidx = (size_t)(fbase + (q - p - 1)) * EMB + lane;
            obase[oidx] = (a0 + a1) + (a2 + a3);   // coalesced 256B store
        }
    }
}

extern "C" void kernel_launch(void* const* d_in, const int* in_sizes, int n_in,
                              void* d_out, int out_size, void* d_ws, size_t ws_size,
                              hipStream_t stream) {
    const float* emb = (const float*)d_in[0];
    float* out = (float*)d_out;

    const int batch = in_sizes[0] / (NF * EMB);
    holo_conv_kernel<<<batch, 256, 0, stream>>>(emb, out);
}

// Round 4
// 195.183 us; speedup vs baseline: 5.5370x; 2.3256x over previous
//
#include <hip/hip_runtime.h>

#define NF    39
#define EMB   64
#define NPAIR 741   // C(39,2)

typedef short bf16x8 __attribute__((ext_vector_type(8)));
typedef float f32x4  __attribute__((ext_vector_type(4)));

union FragU { uint32_t u[4]; bf16x8 v; };

// out[b, pair(p,q), n] = sum_m x_p[(n-m)&63] * x_q[m]  (circular convolution)
// As MFMA: D(64xNQ) = A(64x64 circulant of x_p) * B(64xNQ = Y columns), bf16.
// C/D layout (m89-verified): col = lane&15 (q), row = 4*(lane>>4)+reg (n).
// A[row=lane&15][m=8*(lane>>4)+j+32ki]; B[m][col=lane&15]. Any hw k-permutation
// cancels since A and B builds use the identical (lane>>4,j,ki)->m map.
__global__ __launch_bounds__(256) void holo_mfma_kernel(
    const float* __restrict__ emb,   // [B, 39, 64]
    float* __restrict__ out)         // [B, 741, 64]
{
    // xd[p][i] = bf16(x_p[i]);  xs[p][i] = bf16(x_p[(i+1)&63])
    // xs skewed +8 ushorts: keeps 16B alignment, offsets banks by 4.
    __shared__ __align__(16) unsigned short lds[2 * NF * EMB + 8];
    unsigned short* xd = lds;
    unsigned short* xs = lds + NF * EMB + 8;

    const int b   = blockIdx.x;
    const int tid = threadIdx.x;
    const int l   = tid & 63;
    const int w   = tid >> 6;          // wave = n-tile index (0..3)

    const float* __restrict__ ebase = emb + (size_t)b * (NF * EMB);
    float* __restrict__ obase = out + (size_t)b * (size_t)(NPAIR * EMB);

    // ---- stage: 312 chunks of 8 elems; coalesced float4 reads, b128 writes ----
    for (int cid = tid; cid < (NF * EMB) / 8; cid += 256) {
        const int p  = cid >> 3;
        const int s0 = (cid & 7) * 8;
        const float* g = ebase + p * EMB + s0;
        float4 f0 = *(const float4*)g;
        float4 f1 = *(const float4*)(g + 4);
        float  f8 = ebase[p * EMB + ((s0 + 8) & 63)];   // for the shifted copy
        float xv[9] = {f0.x,f0.y,f0.z,f0.w,f1.x,f1.y,f1.z,f1.w,f8};
        uint32_t us[9];
        #pragma unroll
        for (int i = 0; i < 9; ++i) {                    // f32 -> bf16 RNE
            uint32_t bits = __float_as_uint(xv[i]);
            us[i] = (bits + 0x7FFFu + ((bits >> 16) & 1u)) >> 16;
        }
        uint4 dd, de;
        dd.x = us[0] | (us[1] << 16); dd.y = us[2] | (us[3] << 16);
        dd.z = us[4] | (us[5] << 16); dd.w = us[6] | (us[7] << 16);
        de.x = us[1] | (us[2] << 16); de.y = us[3] | (us[4] << 16);
        de.z = us[5] | (us[6] << 16); de.w = us[7] | (us[8] << 16);
        *(uint4*)(xd + p * EMB + s0) = dd;
        *(uint4*)(xs + p * EMB + s0) = de;
    }
    __syncthreads();

    // ---- B fragments (p-independent, built once): B[m][q] = x_q[m] ----
    FragU Bfr[3][2];
    #pragma unroll
    for (int qi = 0; qi < 3; ++qi) {
        const int q = qi * 16 + (l & 15);
        #pragma unroll
        for (int ki = 0; ki < 2; ++ki) {
            if (q < NF) {
                const int m0 = 8 * (l >> 4) + 32 * ki;   // 16B-aligned
                *(uint4*)Bfr[qi][ki].u = *(const uint4*)(xd + q * EMB + m0);
            } else {
                Bfr[qi][ki].u[0] = Bfr[qi][ki].u[1] = Bfr[qi][ki].u[2] = Bfr[qi][ki].u[3] = 0;
            }
        }
    }

    // ---- per-lane circulant-gather offsets (p-invariant) ----
    // A-frag(ki) reg r = {lo: x[(c-2r)&63], hi: x[(c-2r-1)&63]}, c = cb - 32ki.
    // Read 5 aligned dwords D_k at elem (ce-2k)&63 from parity-selected copy;
    // reg r = {lo: D_r.lo, hi: D_{r+1}.hi}.
    const int cb  = (l & 15) + 16 * w - 8 * (l >> 4);
    const int par = cb & 1;                       // same parity for both ki
    const unsigned short* basept = par ? xs : xd; // branch-free VGPR select
    const int ce = cb - par;
    int idx[2][5];
    #pragma unroll
    for (int ki = 0; ki < 2; ++ki)
        #pragma unroll
        for (int k = 0; k < 5; ++k)
            idx[ki][k] = (ce - 32 * ki - 2 * k) & 63;   // even, in [0,62]

    // ---- p loop: gather A, 2 MFMA per live q-tile, predicated store ----
    for (int p = 0; p < NF - 1; ++p) {
        const unsigned short* row = basept + p * EMB;
        FragU A[2];
        #pragma unroll
        for (int ki = 0; ki < 2; ++ki) {
            uint32_t D[5];
            #pragma unroll
            for (int k = 0; k < 5; ++k)
                D[k] = *(const uint32_t*)(row + idx[ki][k]);
            #pragma unroll
            for (int r = 0; r < 4; ++r)
                A[ki].u[r] = (D[r] & 0xFFFFu) | (D[r + 1] & 0xFFFF0000u);
        }

        const int fb = 38 * p - (p * (p - 1)) / 2 - p - 1;  // pairIdx = fb + q
        #pragma unroll
        for (int qi = 0; qi < 3; ++qi) {
            if (qi * 16 + 15 <= p) continue;     // tile fully q<=p: skip (uniform)
            f32x4 acc = {0.f, 0.f, 0.f, 0.f};
            acc = __builtin_amdgcn_mfma_f32_16x16x32_bf16(A[0].v, Bfr[qi][0].v, acc, 0, 0, 0);
            acc = __builtin_amdgcn_mfma_f32_16x16x32_bf16(A[1].v, Bfr[qi][1].v, acc, 0, 0, 0);
            const int q = qi * 16 + (l & 15);
            if (q > p && q < NF) {
                float* ptr = obase + (size_t)(unsigned)(fb + q) * EMB + 16 * w + 4 * (l >> 4);
                *(f32x4*)ptr = acc;              // 16B store, n-contiguous
            }
        }
    }
}

extern "C" void kernel_launch(void* const* d_in, const int* in_sizes, int n_in,
                              void* d_out, int out_size, void* d_ws, size_t ws_size,
                              hipStream_t stream) {
    const float* emb = (const float*)d_in[0];
    float* out = (float*)d_out;
    const int batch = in_sizes[0] / (NF * EMB);
    holo_mfma_kernel<<<batch, 256, 0, stream>>>(emb, out);
}

// Round 5
// 181.595 us; speedup vs baseline: 5.9514x; 1.0748x over previous
//
#include <hip/hip_runtime.h>

#define NF    39
#define EMB   64
#define NPAIR 741   // C(39,2)
#define RS    72    // LDS row stride in ushorts: 64 + 8 replicated tail

typedef short bf16x8 __attribute__((ext_vector_type(8)));
typedef float f32x4  __attribute__((ext_vector_type(4)));

union FragU { uint32_t u[4]; bf16x8 v; };

static __device__ __forceinline__ uint32_t rot16(uint32_t x) {
    return (x >> 16) | (x << 16);   // -> v_alignbit_b32
}

// out[b, pair(p,q), n] = sum_m x_p[(n-m)&63] * x_q[m]  (circular convolution)
// MFMA 16x16x32 bf16: D = A(circulant of x_p) * B(columns = x_q), layout per m89.
// A-frag gather: the 8 bf16 a lane needs are x[c-7..c] = 16 CONTIGUOUS bytes.
// Dual parity copies (xd[i]=x[i], xs[i]=x[i+1]) make the run start at an even
// element -> 4 dword-aligned LDS dwords -> 2x ds_read2_b32 per ki (R4 used
// 5x ds_read_b32 + merges; DS pipe was 59us/CU, the non-overlapped tail above
// the 117us HBM-write floor). Frag reg r = rot16(dword[3-r]).
__global__ __launch_bounds__(256) void holo_mfma_kernel(
    const float* __restrict__ emb,   // [B, 39, 64]
    float* __restrict__ out)         // [B, 741, 64]
{
    __shared__ __align__(16) unsigned short lds[2 * NF * RS];
    unsigned short* xd = lds;             // xd[p][i] = bf16(x_p[i & 63])
    unsigned short* xs = lds + NF * RS;   // xs[p][i] = bf16(x_p[(i+1) & 63])

    const int b   = blockIdx.x;
    const int tid = threadIdx.x;
    const int l   = tid & 63;
    const int w   = tid >> 6;             // wave = n-tile index (0..3)

    const float* __restrict__ ebase = emb + (size_t)b * (NF * EMB);
    float* __restrict__ obase = out + (size_t)b * (size_t)(NPAIR * EMB);

    // ---- stage both bf16 copies incl. tails: 39 rows x 9 chunks of 8 ----
    for (int cid = tid; cid < NF * 9; cid += 256) {
        const int p  = cid / 9;                  // magic-mul
        const int s0 = (cid - 9 * p) * 8;        // 0,8,...,64
        const int e0 = s0 & 63;
        const float* g = ebase + p * EMB;
        float4 f0 = *(const float4*)(g + e0);            // 4-aligned, no wrap
        float4 f1 = *(const float4*)(g + ((e0 + 4) & 63));
        float  f8 = g[(e0 + 8) & 63];
        float xv[9] = {f0.x,f0.y,f0.z,f0.w,f1.x,f1.y,f1.z,f1.w,f8};
        uint32_t us[9];
        #pragma unroll
        for (int i = 0; i < 9; ++i) {                    // f32 -> bf16 RNE
            uint32_t bits = __float_as_uint(xv[i]);
            us[i] = (bits + 0x7FFFu + ((bits >> 16) & 1u)) >> 16;
        }
        uint4 dd, de;
        dd.x = us[0] | (us[1] << 16); dd.y = us[2] | (us[3] << 16);
        dd.z = us[4] | (us[5] << 16); dd.w = us[6] | (us[7] << 16);
        de.x = us[1] | (us[2] << 16); de.y = us[3] | (us[4] << 16);
        de.z = us[5] | (us[6] << 16); de.w = us[7] | (us[8] << 16);
        *(uint4*)(xd + p * RS + s0) = dd;
        *(uint4*)(xs + p * RS + s0) = de;
    }
    __syncthreads();

    // ---- B fragments (p-independent): B[m][q] = x_q[m], aligned b128 ----
    FragU Bfr[3][2];
    #pragma unroll
    for (int qi = 0; qi < 3; ++qi) {
        const int q = qi * 16 + (l & 15);
        #pragma unroll
        for (int ki = 0; ki < 2; ++ki) {
            if (q < NF) {
                const int m0 = 8 * (l >> 4) + 32 * ki;   // byte 2*m0 % 16 == 0
                *(uint4*)Bfr[qi][ki].u = *(const uint4*)(xd + q * RS + m0);
            } else {
                Bfr[qi][ki].u[0] = Bfr[qi][ki].u[1] = Bfr[qi][ki].u[2] = Bfr[qi][ki].u[3] = 0;
            }
        }
    }

    // ---- p-invariant A-gather bases ----
    // c = cb - 32*ki. Need dwords {x[c-2r-1], x[c-2r]}:
    //   odd  c: xd dword at even element c-2r-1
    //   even c: xs dword at even element c-2r-2   (xs[j] = x[j+1])
    // -> 16B run at even element (c-8+par)&63 of (par ? xd : xs).
    const int cb  = (l & 15) + 16 * w - 8 * (l >> 4);
    const int par = cb & 1;
    const unsigned short* base0 = par ? xd : xs;        // NOTE: roles swapped vs R4
    const unsigned short* rp0 = base0 + ((cb - 8  + par) & 63);   // ki=0, even
    const unsigned short* rp1 = base0 + ((cb - 40 + par) & 63);   // ki=1, even

    // ---- p loop: 2 LDS 16B-runs -> rot16 -> up to 3 q-tiles of 2 MFMA ----
    for (int p = 0; p < NF - 1; ++p) {
        const uint32_t* q0 = (const uint32_t*)(rp0 + p * RS);  // 4B-aligned
        const uint32_t* q1 = (const uint32_t*)(rp1 + p * RS);
        uint32_t w0[4], w1[4];
        #pragma unroll
        for (int k = 0; k < 4; ++k) w0[k] = q0[k];   // -> 2x ds_read2_b32
        #pragma unroll
        for (int k = 0; k < 4; ++k) w1[k] = q1[k];

        FragU A[2];
        #pragma unroll
        for (int r = 0; r < 4; ++r) A[0].u[r] = rot16(w0[3 - r]);
        #pragma unroll
        for (int r = 0; r < 4; ++r) A[1].u[r] = rot16(w1[3 - r]);

        const int fb = 38 * p - (p * (p - 1)) / 2 - p - 1;  // pairIdx = fb + q
        #pragma unroll
        for (int qi = 0; qi < 3; ++qi) {
            if (qi * 16 + 15 <= p) continue;     // tile fully q<=p: uniform skip
            f32x4 acc = {0.f, 0.f, 0.f, 0.f};
            acc = __builtin_amdgcn_mfma_f32_16x16x32_bf16(A[0].v, Bfr[qi][0].v, acc, 0, 0, 0);
            acc = __builtin_amdgcn_mfma_f32_16x16x32_bf16(A[1].v, Bfr[qi][1].v, acc, 0, 0, 0);
            const int q = qi * 16 + (l & 15);
            if (q > p && q < NF) {
                float* ptr = obase + (size_t)(unsigned)(fb + q) * EMB + 16 * w + 4 * (l >> 4);
                *(f32x4*)ptr = acc;              // 16B store; 64B/4-lane group
            }
        }
    }
}

extern "C" void kernel_launch(void* const* d_in, const int* in_sizes, int n_in,
                              void* d_out, int out_size, void* d_ws, size_t ws_size,
                              hipStream_t stream) {
    const float* emb = (const float*)d_in[0];
    float* out = (float*)d_out;
    const int batch = in_sizes[0] / (NF * EMB);
    holo_mfma_kernel<<<batch, 256, 0, stream>>>(emb, out);
}

// Round 6
// 172.051 us; speedup vs baseline: 6.2815x; 1.0555x over previous
//
#include <hip/hip_runtime.h>

#define NF    39
#define EMB   64
#define NPAIR 741   // C(39,2)
#define RS    72    // LDS row stride in ushorts: 64 + 8 replicated tail

// LDS layout (ushort offsets). xssw placed +2848 from xdsw: 1424 dwords
// == 16 mod 32 banks -> odd-lane (xdsw) and even-lane (xssw) bank runs
// disjoint (R5's +28-bank offset gave 3-4-way conflicts).
#define XD    0                 // xd[p][i]   = bf16(x[i&63])           (B-frags)
#define XDSW  2816              // xdsw[p][2j]=x[2j+1], [2j+1]=x[2j]    (A, odd c)
#define XSSW  (2816 + 2848)     // xssw[p][2j]=x[2j+2], [2j+1]=x[2j+1]  (A, even c)
#define LDSZ  (XSSW + NF * RS)  // 8472 ushorts = 16944 B

typedef short bf16x8 __attribute__((ext_vector_type(8)));
typedef float f32x4  __attribute__((ext_vector_type(4)));

union FragU { uint32_t u[4]; bf16x8 v; };

// out[b, pair(p,q), n] = sum_m x_p[(n-m)&63] * x_q[m]  (circular convolution)
// MFMA 16x16x32 bf16, D = A(circulant x_p) * B(cols x_q), C/D layout per m89.
// A-frag = 16 contiguous bytes x[c-7..c]; pair-swapped parity copies make the
// read start even AND deliver the 16-bit-rotated dwords directly:
//   A.u[r] = dword[3-r]   (zero VALU; R5 needed 8x rot16 per p).
__global__ __launch_bounds__(256) void holo_mfma_kernel(
    const float* __restrict__ emb,   // [B, 39, 64]
    float* __restrict__ out)         // [B, 741, 64]
{
    __shared__ __align__(16) unsigned short lds[LDSZ];

    const int b   = blockIdx.x;
    const int tid = threadIdx.x;
    const int l   = tid & 63;
    const int w   = tid >> 6;             // wave = n-tile index (0..3)

    const float* __restrict__ ebase = emb + (size_t)b * (NF * EMB);
    float* __restrict__ obase = out + (size_t)b * (size_t)(NPAIR * EMB);

    // ---- stage 3 bf16 copies incl. 8-elem wrap tails: 39 rows x 9 chunks ----
    for (int cid = tid; cid < NF * 9; cid += 256) {
        const int p  = cid / 9;
        const int s0 = (cid - 9 * p) * 8;        // 0,8,...,64
        const int e0 = s0 & 63;
        const float* g = ebase + p * EMB;
        float4 f0 = *(const float4*)(g + e0);
        float4 f1 = *(const float4*)(g + ((e0 + 4) & 63));
        float  f8 = g[(e0 + 8) & 63];
        float xv[9] = {f0.x,f0.y,f0.z,f0.w,f1.x,f1.y,f1.z,f1.w,f8};
        uint32_t us[9];
        #pragma unroll
        for (int i = 0; i < 9; ++i) {            // f32 -> bf16 RNE
            uint32_t bits = __float_as_uint(xv[i]);
            us[i] = (bits + 0x7FFFu + ((bits >> 16) & 1u)) >> 16;
        }
        uint4 dd, dw, de;
        dd.x = us[0] | (us[1] << 16); dd.y = us[2] | (us[3] << 16);   // xd
        dd.z = us[4] | (us[5] << 16); dd.w = us[6] | (us[7] << 16);
        dw.x = us[1] | (us[0] << 16); dw.y = us[3] | (us[2] << 16);   // xd swapped
        dw.z = us[5] | (us[4] << 16); dw.w = us[7] | (us[6] << 16);
        de.x = us[2] | (us[1] << 16); de.y = us[4] | (us[3] << 16);   // xs swapped
        de.z = us[6] | (us[5] << 16); de.w = us[8] | (us[7] << 16);
        *(uint4*)(lds + XD   + p * RS + s0) = dd;
        *(uint4*)(lds + XDSW + p * RS + s0) = dw;
        *(uint4*)(lds + XSSW + p * RS + s0) = de;
    }
    __syncthreads();

    // ---- B fragments (p-independent): B[m][q] = x_q[m], aligned b128 ----
    FragU Bfr[3][2];
    #pragma unroll
    for (int qi = 0; qi < 3; ++qi) {
        const int q = qi * 16 + (l & 15);
        #pragma unroll
        for (int ki = 0; ki < 2; ++ki) {
            if (q < NF) {
                const int m0 = 8 * (l >> 4) + 32 * ki;
                *(uint4*)Bfr[qi][ki].u = *(const uint4*)(lds + XD + q * RS + m0);
            } else {
                Bfr[qi][ki].u[0] = Bfr[qi][ki].u[1] = Bfr[qi][ki].u[2] = Bfr[qi][ki].u[3] = 0;
            }
        }
    }

    // ---- p-invariant A-gather bases (16B run at even element, parity copy) ----
    const int cb  = (l & 15) + 16 * w - 8 * (l >> 4);
    const int par = cb & 1;
    const unsigned short* baseA = lds + (par ? XDSW : XSSW);
    const uint32_t* r0 = (const uint32_t*)(baseA + ((cb - 8  + par) & 63)); // ki=0
    const uint32_t* r1 = (const uint32_t*)(baseA + ((cb - 40 + par) & 63)); // ki=1

    auto LOAD = [&](int p, uint32_t d0[4], uint32_t d1[4]) {
        const uint32_t* a = r0 + p * (RS / 2);
        const uint32_t* c = r1 + p * (RS / 2);
        #pragma unroll
        for (int k = 0; k < 4; ++k) d0[k] = a[k];   // -> 2x ds_read2_b32
        #pragma unroll
        for (int k = 0; k < 4; ++k) d1[k] = c[k];
    };

    auto COMPUTE = [&](int p, const uint32_t d0[4], const uint32_t d1[4]) {
        FragU A0, A1;
        #pragma unroll
        for (int r = 0; r < 4; ++r) { A0.u[r] = d0[3 - r]; A1.u[r] = d1[3 - r]; }
        const int fb = 38 * p - (p * (p - 1)) / 2 - p - 1;   // pairIdx = fb + q
        #pragma unroll
        for (int qi = 0; qi < 3; ++qi) {
            if (qi * 16 + 15 <= p) continue;   // tile fully q<=p: uniform skip
            f32x4 acc = {0.f, 0.f, 0.f, 0.f};
            acc = __builtin_amdgcn_mfma_f32_16x16x32_bf16(A0.v, Bfr[qi][0].v, acc, 0, 0, 0);
            acc = __builtin_amdgcn_mfma_f32_16x16x32_bf16(A1.v, Bfr[qi][1].v, acc, 0, 0, 0);
            const int q = qi * 16 + (l & 15);
            if (q > p && q < NF) {
                float* ptr = obase + (size_t)(unsigned)(fb + q) * EMB + 16 * w + 4 * (l >> 4);
                *(f32x4*)ptr = acc;            // 16B/lane; 64B contiguous per 16-lane group
            }
        }
    };

    // ---- software-pipelined p loop (unroll 2, double register buffer) ----
    uint32_t A0a[4], A1a[4], A0b[4], A1b[4];
    LOAD(0, A0a, A1a);
    for (int p = 0; p < NF - 1; p += 2) {
        LOAD(p + 1, A0b, A1b);                 // p+1 <= 37 always (38 iters)
        COMPUTE(p, A0a, A1a);
        if (p + 2 < NF - 1) LOAD(p + 2, A0a, A1a);
        COMPUTE(p + 1, A0b, A1b);
    }
}

extern "C" void kernel_launch(void* const* d_in, const int* in_sizes, int n_in,
                              void* d_out, int out_size, void* d_ws, size_t ws_size,
                              hipStream_t stream) {
    const float* emb = (const float*)d_in[0];
    float* out = (float*)d_out;
    const int batch = in_sizes[0] / (NF * EMB);
    holo_mfma_kernel<<<batch, 256, 0, stream>>>(emb, out);
}

// Round 7
// 166.957 us; speedup vs baseline: 6.4731x; 1.0305x over previous
//
#include <hip/hip_runtime.h>

#define NF    39
#define EMB   64
#define NPAIR 741   // C(39,2)
#define RS    72    // LDS row stride in ushorts: 64 + 8 replicated tail

// LDS layout (ushort offsets). xssw at +2848 from xdsw (== 16 mod 32 banks):
// odd-lane and even-lane bank runs disjoint.
#define XD    0                 // xd[p][i]   = bf16(x[i&63])           (B-frags)
#define XDSW  2816              // xdsw[p][2j]=x[2j+1], [2j+1]=x[2j]    (A, odd c)
#define XSSW  (2816 + 2848)     // xssw[p][2j]=x[2j+2], [2j+1]=x[2j+1]  (A, even c)
#define LDSZ  (XSSW + NF * RS)  // 8472 ushorts = 16944 B

typedef short bf16x8 __attribute__((ext_vector_type(8)));
typedef float f32x4  __attribute__((ext_vector_type(4)));

union FragU { uint32_t u[4]; bf16x8 v; };

// out[b, pair(p,q), n] = sum_m x_p[(n-m)&63] * x_q[m]  (circular convolution)
// MFMA 16x16x32 bf16, D = A(circulant x_p) * B(cols x_q), C/D layout per m89.
//
// R7: each WAVE owns p in {w, w+4, ...} and computes ALL 4 n-tiles x 3 q-tiles.
//  - stores: per (p,qi) 4 back-to-back f32x4 stores complete each q-row's
//    full 256B from ONE wave (R6 split rows across waves -> 64B chunks whose
//    128B-line completion depended on sibling-wave timing; write BW 4.4 vs
//    6.7 TB/s fill).
//  - A-gather: n-tile t, k-slice ki needs the 16B run at element offset
//    (16t - 32ki) mod 64 from the lane base -> only 4 DISTINCT runs {0,16,32,48}
//    serve all 8 (t,ki) slots: frag(t,ki) = run[(t - 2ki) & 3]. DS halves.
__global__ __launch_bounds__(256) void holo_mfma_kernel(
    const float* __restrict__ emb,   // [B, 39, 64]
    float* __restrict__ out)         // [B, 741, 64]
{
    __shared__ __align__(16) unsigned short lds[LDSZ];

    const int b   = blockIdx.x;
    const int tid = threadIdx.x;
    const int l   = tid & 63;
    const int w   = tid >> 6;             // wave = p-stripe index (0..3)
    const int g   = l >> 4;

    const float* __restrict__ ebase = emb + (size_t)b * (NF * EMB);
    float* __restrict__ obase = out + (size_t)b * (size_t)(NPAIR * EMB);

    // ---- stage 3 bf16 copies incl. 8-elem wrap tails: 39 rows x 9 chunks ----
    for (int cid = tid; cid < NF * 9; cid += 256) {
        const int p  = cid / 9;
        const int s0 = (cid - 9 * p) * 8;        // 0,8,...,64
        const int e0 = s0 & 63;
        const float* gp = ebase + p * EMB;
        float4 f0 = *(const float4*)(gp + e0);
        float4 f1 = *(const float4*)(gp + ((e0 + 4) & 63));
        float  f8 = gp[(e0 + 8) & 63];
        float xv[9] = {f0.x,f0.y,f0.z,f0.w,f1.x,f1.y,f1.z,f1.w,f8};
        uint32_t us[9];
        #pragma unroll
        for (int i = 0; i < 9; ++i) {            // f32 -> bf16 RNE
            uint32_t bits = __float_as_uint(xv[i]);
            us[i] = (bits + 0x7FFFu + ((bits >> 16) & 1u)) >> 16;
        }
        uint4 dd, dw, de;
        dd.x = us[0] | (us[1] << 16); dd.y = us[2] | (us[3] << 16);   // xd
        dd.z = us[4] | (us[5] << 16); dd.w = us[6] | (us[7] << 16);
        dw.x = us[1] | (us[0] << 16); dw.y = us[3] | (us[2] << 16);   // xd swapped
        dw.z = us[5] | (us[4] << 16); dw.w = us[7] | (us[6] << 16);
        de.x = us[2] | (us[1] << 16); de.y = us[4] | (us[3] << 16);   // xs swapped
        de.z = us[6] | (us[5] << 16); de.w = us[8] | (us[7] << 16);
        *(uint4*)(lds + XD   + p * RS + s0) = dd;
        *(uint4*)(lds + XDSW + p * RS + s0) = dw;
        *(uint4*)(lds + XSSW + p * RS + s0) = de;
    }
    __syncthreads();

    // ---- B fragments (p-independent): B[m][q] = x_q[m], aligned b128 ----
    FragU Bfr[3][2];
    #pragma unroll
    for (int qi = 0; qi < 3; ++qi) {
        const int q = qi * 16 + (l & 15);
        #pragma unroll
        for (int ki = 0; ki < 2; ++ki) {
            if (q < NF) {
                const int m0 = 8 * g + 32 * ki;
                *(uint4*)Bfr[qi][ki].u = *(const uint4*)(lds + XD + q * RS + m0);
            } else {
                Bfr[qi][ki].u[0] = Bfr[qi][ki].u[1] = Bfr[qi][ki].u[2] = Bfr[qi][ki].u[3] = 0;
            }
        }
    }

    // ---- p-invariant A-gather bases: 4 runs per lane per p ----
    // par = parity of (l&15 - 8g) = l&1; base element e0 even.
    const int par = l & 1;
    const unsigned short* baseA = lds + (par ? XDSW : XSSW);
    const int e0 = ((l & 15) - 8 * g - 8 + par) & 63;
    const uint32_t* rp[4];
    #pragma unroll
    for (int k = 0; k < 4; ++k)
        rp[k] = (const uint32_t*)(baseA + ((e0 + 16 * k) & 63));

    auto LOADP = [&](int p, uint32_t R[4][4]) {
        const int d = p * (RS / 2);
        #pragma unroll
        for (int k = 0; k < 4; ++k)
            #pragma unroll
            for (int j = 0; j < 4; ++j)
                R[k][j] = rp[k][d + j];          // -> 2x ds_read2_b32 per run
    };

    auto COMP = [&](int p, const uint32_t R[4][4]) {
        FragU A[4];
        #pragma unroll
        for (int k = 0; k < 4; ++k)
            #pragma unroll
            for (int r = 0; r < 4; ++r) A[k].u[r] = R[k][3 - r];
        const int fb = 38 * p - (p * (p - 1)) / 2 - p - 1;   // pairIdx = fb + q
        const int q  = (l & 15);
        #pragma unroll
        for (int qi = 0; qi < 3; ++qi) {
            if (qi * 16 + 15 <= p) continue;     // tile fully q<=p: uniform skip
            f32x4 acc[4];
            #pragma unroll
            for (int t = 0; t < 4; ++t) {
                acc[t] = f32x4{0.f, 0.f, 0.f, 0.f};
                acc[t] = __builtin_amdgcn_mfma_f32_16x16x32_bf16(
                             A[t].v,           Bfr[qi][0].v, acc[t], 0, 0, 0);
                acc[t] = __builtin_amdgcn_mfma_f32_16x16x32_bf16(
                             A[(t + 2) & 3].v, Bfr[qi][1].v, acc[t], 0, 0, 0);
            }
            const int qq = qi * 16 + q;
            if (qq > p && qq < NF) {
                float* base = obase + (size_t)(unsigned)(fb + qq) * EMB + 4 * g;
                #pragma unroll
                for (int t = 0; t < 4; ++t)
                    *(f32x4*)(base + 16 * t) = acc[t];   // row filled 256B by this wave
            }
        }
    };

    // ---- per-wave p loop (stride 4), software-pipelined 1 ahead ----
    uint32_t Ra[4][4], Rb[4][4];
    int p = w;
    if (p < NF - 1) LOADP(p, Ra);
    for (; p < NF - 1; p += 8) {
        if (p + 4 < NF - 1) LOADP(p + 4, Rb);
        COMP(p, Ra);
        if (p + 8 < NF - 1) LOADP(p + 8, Ra);
        if (p + 4 < NF - 1) COMP(p + 4, Rb);
    }
}

extern "C" void kernel_launch(void* const* d_in, const int* in_sizes, int n_in,
                              void* d_out, int out_size, void* d_ws, size_t ws_size,
                              hipStream_t stream) {
    const float* emb = (const float*)d_in[0];
    float* out = (float*)d_out;
    const int batch = in_sizes[0] / (NF * EMB);
    holo_mfma_kernel<<<batch, 256, 0, stream>>>(emb, out);
}